// Round 16
// baseline (285.969 us; speedup 1.0000x reference)
//
#include <hip/hip_runtime.h>
#include <hip/hip_fp16.h>

// ImplicitPointHead fused (MI355X / gfx950) — round 16
// r15: B-per-point halving at 8 waves/CU lost (~220) -> TLP matters more.
// Cycle model: LDS pipe ~68% busy = top consumer; A-frag reads 8x-duplicated.
// This config cuts A-dup 8->4 WITHOUT doubling B (r7's mistake: point-split;
// here: channel-split only): 256-thr blocks (4 waves), PT=64, wave=64pts x
// 64ch. Weights once per block, B-per-CU unchanged, acc[4][4] = 16 MFMAs per
// 4A+4B group. 2 blocks/CU overlap phases. r11 asm machinery: 4-deep x 4-wide
// vmcnt ring (issue->16 in flight, wait 12), raw barriers, x-layer prologues.

#define NI      128
#define NPTS    2048
#define CH      256
#define NPARAM  263169
#define PT      64
#define NTILES  (NPTS / PT)     // 32
#define ROWS    536             // 67x16B per row (odd -> minimal b128 aliasing)

#define WOFF0   0
#define WOFF1   131072
#define WOFF2   196608
#define WOFF3   262144
#define BOFF0   262400
#define BOFF1   262656
#define BOFF2   262912
#define BOFF3   263168

#define PI_L0   0        // 16 ks * 16 cb * 64 lane * 8
#define PI_L1   131072
#define PI_L2   196608
#define PI_L3   262144
#define WS_PER_INST 262400
#define WS_BYTES ((size_t)NI * WS_PER_INST * 2)

typedef __fp16   h16x2 __attribute__((ext_vector_type(2)));
typedef _Float16 f16x8 __attribute__((ext_vector_type(8)));
typedef float    f32x4 __attribute__((ext_vector_type(4)));

union pack8 { h16x2 h[4]; f16x8 v; };

// ---------------- prep: params fp32 -> fragment-ordered fp16 (r11, unchanged) ----
// Frag cb, lane l covers co = (cb>>1)*32 + 2*(l&15) + (cb&1); k = ks*32+(l>>4)*8.
__global__ __launch_bounds__(256) void iph_prep(
    const float* __restrict__ params, _Float16* __restrict__ wsw)
{
    const int inst = blockIdx.y;
    const int r = blockIdx.x * 256 + threadIdx.x;
    if (r >= 32800) return;
    const float* __restrict__ P = params + (size_t)inst * NPARAM;
    _Float16* __restrict__ W = wsw + (size_t)inst * WS_PER_INST;

    int rl, woff, K, dst;
    if (r < 16384)      { rl = r;         woff = WOFF0; K = 512; dst = PI_L0; }
    else if (r < 24576) { rl = r - 16384; woff = WOFF1; K = 256; dst = PI_L1; }
    else if (r < 32768) { rl = r - 24576; woff = WOFF2; K = 256; dst = PI_L2; }
    else {
        const int e = (r - 32768) * 8;
        f16x8 v;
        #pragma unroll
        for (int j = 0; j < 8; ++j) v[j] = (_Float16)P[WOFF3 + e + j];
        *(f16x8*)&W[PI_L3 + e] = v;
        return;
    }
    const int e    = rl * 8;
    const int lane = rl & 63;
    const int cb   = (rl >> 6) & 15;
    const int ks   = rl >> 10;
    const int co   = (cb >> 1) * 32 + 2 * (lane & 15) + (cb & 1);
    const int k    = ks * 32 + (lane >> 4) * 8;
    const float* __restrict__ src = P + woff + co * K + k;
    f16x8 v;
    #pragma unroll
    for (int j = 0; j < 8; ++j) v[j] = (_Float16)src[j];
    *(f16x8*)&W[dst + e] = v;
}

// ---------------- asm pipeline primitives ----------------
// 4 B-frags (one ks for a 64-ch wave): offsets 0,1024,2048,3072 B
__device__ __forceinline__ void issue_b4(const _Float16* p,
                                         f16x8& r0, f16x8& r1, f16x8& r2, f16x8& r3) {
    const unsigned long long a = (unsigned long long)p;
    asm volatile("global_load_dwordx4 %0, %4, off\n\t"
                 "global_load_dwordx4 %1, %4, off offset:1024\n\t"
                 "global_load_dwordx4 %2, %4, off offset:2048\n\t"
                 "global_load_dwordx4 %3, %4, off offset:3072"
                 : "=&v"(r0), "=&v"(r1), "=&v"(r2), "=&v"(r3)
                 : "v"(a));
}

template<int N>
__device__ __forceinline__ void wait_vm() {
    if constexpr (N >= 12)     asm volatile("s_waitcnt vmcnt(12)" ::: "memory");
    else if constexpr (N == 8) asm volatile("s_waitcnt vmcnt(8)" ::: "memory");
    else if constexpr (N == 4) asm volatile("s_waitcnt vmcnt(4)" ::: "memory");
    else                       asm volatile("s_waitcnt vmcnt(0)" ::: "memory");
    __builtin_amdgcn_sched_barrier(0);   // rule #18
}

__device__ __forceinline__ void lgkm0_barrier() {
    asm volatile("s_waitcnt lgkmcnt(0)" ::: "memory");
    __builtin_amdgcn_s_barrier();        // raw: vmcnt NOT drained
}

// prologue: issue ks 0..2 (12 loads in flight)
__device__ __forceinline__ void issue_pro(const _Float16* bp, f16x8 (&q)[4][4]) {
    #pragma unroll
    for (int i = 0; i < 3; ++i)
        issue_b4(bp + i * 8192, q[i][0], q[i][1], q[i][2], q[i][3]);
}

// ---------------- pipelined GEMM (wave = 64pts x 64ch) ----------------
// Requires issue_pro(bp,q) earlier (ks 0..2 in flight).
template<int NKS>
__device__ __forceinline__ void gemm_pipe(
    f32x4 (&acc)[4][4], const _Float16* bp, const _Float16* ap, f16x8 (&q)[4][4])
{
    #pragma unroll
    for (int ks = 0; ks < NKS; ++ks) {
        f16x8 a[4];
        #pragma unroll
        for (int mt = 0; mt < 4; ++mt)
            a[mt] = *(const f16x8*)(ap + mt * 16 * ROWS + ks * 32);
        // issue first: in flight = ks..ks+3 (16 loads)
        if (ks + 3 < NKS) {
            const int s = (ks + 3) & 3;
            issue_b4(bp + (ks + 3) * 8192, q[s][0], q[s][1], q[s][2], q[s][3]);
        }
        // wait: drain exactly ks's 4 loads
        const int rem = NKS - 1 - ks;
        if (rem >= 3)      wait_vm<12>();
        else if (rem == 2) wait_vm<8>();
        else if (rem == 1) wait_vm<4>();
        else               wait_vm<0>();
        const int c = ks & 3;
        __builtin_amdgcn_s_setprio(1);
        #pragma unroll
        for (int mt = 0; mt < 4; ++mt) {
            acc[mt][0] = __builtin_amdgcn_mfma_f32_16x16x32_f16(a[mt], q[c][0], acc[mt][0], 0, 0, 0);
            acc[mt][1] = __builtin_amdgcn_mfma_f32_16x16x32_f16(a[mt], q[c][1], acc[mt][1], 0, 0, 0);
            acc[mt][2] = __builtin_amdgcn_mfma_f32_16x16x32_f16(a[mt], q[c][2], acc[mt][2], 0, 0, 0);
            acc[mt][3] = __builtin_amdgcn_mfma_f32_16x16x32_f16(a[mt], q[c][3], acc[mt][3], 0, 0, 0);
        }
        __builtin_amdgcn_s_setprio(0);
    }
}

// ---------------- main fused kernel (256 threads, 4 waves, PT=64) ----------------
template<bool PREPPED>
__global__ __launch_bounds__(256) void iph_main(
    const float* __restrict__ feat,     // [128][256][2048]
    const float* __restrict__ coords,   // [128][2048][2]
    const float* __restrict__ params,   // [128][263169]
    const _Float16* __restrict__ wsw,   // fragment-ordered f16 weights
    const float* __restrict__ peg,      // [2][128]
    float* __restrict__ out)            // [128][1][2048]
{
    __shared__ _Float16 X[PT * ROWS];   // 68608 B
    __shared__ float    partial[4][PT]; // 1 KB -> 69632 B, 2 blocks/CU

    const int bid  = blockIdx.x;        // 4096 blocks
    const int inst = (bid & 7) | ((bid >> 8) << 3);
    const int tile = (bid >> 3) & 31;
    const int p0   = tile * PT;
    const int tid  = threadIdx.x;
    const int lane = tid & 63;
    const int wave = tid >> 6;          // 0..3, owns ch wave*64..wave*64+63
    const int l15  = lane & 15;
    const int hi   = lane >> 4;
    const float* __restrict__ P = params + (size_t)inst * NPARAM;
    const _Float16* __restrict__ WI = wsw + (size_t)inst * WS_PER_INST;

    const _Float16* bp0 = WI + PI_L0 + ((wave * 4) * 64 + lane) * 8;
    const _Float16* bp1 = WI + PI_L1 + ((wave * 4) * 64 + lane) * 8;
    const _Float16* bp2 = WI + PI_L2 + ((wave * 4) * 64 + lane) * 8;
    const _Float16* ap  = &X[l15 * ROWS + hi * 8];

    // hoist per-lane scalars (keeps vmcnt regions clean)
    const float2 b0l = *(const float2*)&P[BOFF0 + wave * 64 + 2 * l15];
    const float2 b0h = *(const float2*)&P[BOFF0 + wave * 64 + 32 + 2 * l15];
    const float2 b1l = *(const float2*)&P[BOFF1 + wave * 64 + 2 * l15];
    const float2 b1h = *(const float2*)&P[BOFF1 + wave * 64 + 32 + 2 * l15];
    const float2 b2l = *(const float2*)&P[BOFF2 + wave * 64 + 2 * l15];
    const float2 b2h = *(const float2*)&P[BOFF2 + wave * 64 + 32 + 2 * l15];
    const float2 w3l = *(const float2*)&P[WOFF3 + wave * 64 + 2 * l15];
    const float2 w3h = *(const float2*)&P[WOFF3 + wave * 64 + 32 + 2 * l15];

    f16x8 qa[4][4], qb[4][4], qc[4][4];

    // L0 B-prologue at kernel top: flies during PE + staging
    if (PREPPED) issue_pro(bp0, qa);

    // ---- positional encoding -> X[pt][0..255]  (4 threads/pt, 32 freqs each)
    {
        const int pt   = tid >> 2;     // 0..63
        const int part = tid & 3;      // 32 freqs each
        const float2 cc = *(const float2*)&coords[((size_t)inst * NPTS + p0 + pt) * 2];
        const float a = 2.f * cc.x - 1.f;
        const float b = 2.f * cc.y - 1.f;
        float sv[32], cv[32];
        #pragma unroll
        for (int j = 0; j < 32; ++j) {
            const int f = part * 32 + j;
            float locr = a * peg[f] + b * peg[128 + f];
            locr -= floorf(locr);                        // period-1 reduction
            sv[j] = __builtin_amdgcn_sinf(locr);         // sin(2*pi*x)
            cv[j] = __builtin_amdgcn_cosf(locr);
        }
        _Float16* base = &X[pt * ROWS + part * 32];
        #pragma unroll
        for (int c = 0; c < 4; ++c) {
            pack8 ps, pc;
            #pragma unroll
            for (int q = 0; q < 4; ++q) {
                ps.h[q] = __builtin_amdgcn_cvt_pkrtz(sv[c*8 + 2*q], sv[c*8 + 2*q + 1]);
                pc.h[q] = __builtin_amdgcn_cvt_pkrtz(cv[c*8 + 2*q], cv[c*8 + 2*q + 1]);
            }
            *(f16x8*)(base + c * 8)       = ps.v;
            *(f16x8*)(base + 128 + c * 8) = pc.v;
        }
    }
    // ---- features -> X[pt][256..511]; thread: pt = tid&63, 64 ch (8xb128)
    {
        const int p  = tid & 63;
        const int cg = tid >> 6;       // 0..3 -> channels cg*64..cg*64+63
        const float* fbase = feat + (size_t)inst * CH * NPTS + (size_t)(cg * 64) * NPTS + p0 + p;
        #pragma unroll
        for (int s = 0; s < 8; ++s) {
            float w8[8];
            #pragma unroll
            for (int j = 0; j < 8; ++j)
                w8[j] = fbase[(size_t)(s * 8 + j) * NPTS];
            pack8 pk;
            #pragma unroll
            for (int q = 0; q < 4; ++q)
                pk.h[q] = __builtin_amdgcn_cvt_pkrtz(w8[2*q], w8[2*q + 1]);
            *(f16x8*)&X[p * ROWS + 256 + cg * 64 + s * 8] = pk.v;
        }
    }
    lgkm0_barrier();   // publish X; raw barrier keeps L0 B-queue in flight

    // epilogue: relu(acc+b) -> X (even/odd half2 writes); C/D map (m89)
    // nt 0,1 -> ch wave*64 + 2*l15 (+1); nt 2,3 -> +32
    auto write_epilogue = [&](f32x4 (&acc)[4][4], const float2 bl, const float2 bh) {
        #pragma unroll
        for (int mt = 0; mt < 4; ++mt) {
            #pragma unroll
            for (int r = 0; r < 4; ++r) {
                const int pt = mt * 16 + hi * 4 + r;
                const float v0 = fmaxf(acc[mt][0][r] + bl.x, 0.f);
                const float v1 = fmaxf(acc[mt][1][r] + bl.y, 0.f);
                const float v2 = fmaxf(acc[mt][2][r] + bh.x, 0.f);
                const float v3 = fmaxf(acc[mt][3][r] + bh.y, 0.f);
                *(h16x2*)&X[pt * ROWS + wave * 64 + 2 * l15]      = __builtin_amdgcn_cvt_pkrtz(v0, v1);
                *(h16x2*)&X[pt * ROWS + wave * 64 + 32 + 2 * l15] = __builtin_amdgcn_cvt_pkrtz(v2, v3);
            }
        }
    };

    // fallback (no prep): fp32 weights converted in-loop
    auto gemm_simple = [&](f32x4 (&acc)[4][4], const float* pw, const int K) {
        for (int ks = 0; ks < (K >> 5); ++ks) {
            f16x8 bfrag[4];
            #pragma unroll
            for (int nt = 0; nt < 4; ++nt) {
                const int cb = wave * 4 + nt;
                const int co = (cb >> 1) * 32 + 2 * l15 + (cb & 1);
                const float* wp = pw + (size_t)co * K + ks * 32 + hi * 8;
                float w8[8];
                __builtin_memcpy(w8, wp, 32);
                f16x8 bb;
                #pragma unroll
                for (int j = 0; j < 8; ++j) bb[j] = (_Float16)w8[j];
                bfrag[nt] = bb;
            }
            #pragma unroll
            for (int mt = 0; mt < 4; ++mt) {
                f16x8 af = *(const f16x8*)&X[(mt * 16 + l15) * ROWS + ks * 32 + hi * 8];
                #pragma unroll
                for (int nt = 0; nt < 4; ++nt)
                    acc[mt][nt] = __builtin_amdgcn_mfma_f32_16x16x32_f16(af, bfrag[nt], acc[mt][nt], 0, 0, 0);
            }
        }
    };

    // ---- L0
    {
        f32x4 acc[4][4];
        #pragma unroll
        for (int mt = 0; mt < 4; ++mt)
            #pragma unroll
            for (int nt = 0; nt < 4; ++nt)
                acc[mt][nt] = (f32x4){0.f, 0.f, 0.f, 0.f};
        if (PREPPED) gemm_pipe<16>(acc, bp0, ap, qa);
        else         gemm_simple(acc, P + WOFF0, 512);
        if (PREPPED) issue_pro(bp1, qb);       // L1 prologue flies over epilogue
        __builtin_amdgcn_s_barrier();           // all waves done reading X
        write_epilogue(acc, b0l, b0h);
        lgkm0_barrier();                        // publish L0 output
    }
    // ---- L1
    {
        f32x4 acc[4][4];
        #pragma unroll
        for (int mt = 0; mt < 4; ++mt)
            #pragma unroll
            for (int nt = 0; nt < 4; ++nt)
                acc[mt][nt] = (f32x4){0.f, 0.f, 0.f, 0.f};
        if (PREPPED) gemm_pipe<8>(acc, bp1, ap, qb);
        else         gemm_simple(acc, P + WOFF1, 256);
        if (PREPPED) issue_pro(bp2, qc);       // L2 prologue
        __builtin_amdgcn_s_barrier();
        write_epilogue(acc, b1l, b1h);
        lgkm0_barrier();
    }
    // ---- L2 + L3 fused: partial[wave][pt] = sum_{ch in wave's 64} w3[ch]*relu(acc+b2)
    {
        f32x4 acc[4][4];
        #pragma unroll
        for (int mt = 0; mt < 4; ++mt)
            #pragma unroll
            for (int nt = 0; nt < 4; ++nt)
                acc[mt][nt] = (f32x4){0.f, 0.f, 0.f, 0.f};
        if (PREPPED) gemm_pipe<8>(acc, bp2, ap, qc);
        else         gemm_simple(acc, P + WOFF2, 256);
        #pragma unroll
        for (int mt = 0; mt < 4; ++mt) {
            #pragma unroll
            for (int r = 0; r < 4; ++r) {
                const float v0 = fmaxf(acc[mt][0][r] + b2l.x, 0.f);
                const float v1 = fmaxf(acc[mt][1][r] + b2l.y, 0.f);
                const float v2 = fmaxf(acc[mt][2][r] + b2h.x, 0.f);
                const float v3 = fmaxf(acc[mt][3][r] + b2h.y, 0.f);
                float s = v0 * w3l.x + v1 * w3l.y + v2 * w3h.x + v3 * w3h.y;
                s += __shfl_xor(s, 1);
                s += __shfl_xor(s, 2);
                s += __shfl_xor(s, 4);
                s += __shfl_xor(s, 8);
                if (l15 == 0)
                    partial[wave][mt * 16 + hi * 4 + r] = s;
            }
        }
        lgkm0_barrier();                        // publish partials
        if (tid < PT) {
            float s = P[BOFF3];
            #pragma unroll
            for (int w = 0; w < 4; ++w) s += partial[w][tid];
            out[(size_t)inst * NPTS + p0 + tid] = s;
        }
    }
}

extern "C" void kernel_launch(void* const* d_in, const int* in_sizes, int n_in,
                              void* d_out, int out_size, void* d_ws, size_t ws_size,
                              hipStream_t stream) {
    (void)in_sizes; (void)n_in; (void)out_size;
    const float* feat   = (const float*)d_in[0];
    const float* coords = (const float*)d_in[1];
    const float* params = (const float*)d_in[2];
    const float* peg    = (const float*)d_in[3];
    float* out = (float*)d_out;

    dim3 grid(NI * NTILES);   // 4096 blocks
    dim3 block(256);

    if (ws_size >= WS_BYTES) {
        _Float16* wsw = (_Float16*)d_ws;
        iph_prep<<<dim3(129, 128), dim3(256), 0, stream>>>(params, wsw);
        iph_main<true><<<grid, block, 0, stream>>>(feat, coords, params, wsw, peg, out);
    } else {
        iph_main<false><<<grid, block, 0, stream>>>(feat, coords, params,
                                                    (const _Float16*)d_ws, peg, out);
    }
}

// Round 17
// 214.474 us; speedup vs baseline: 1.3334x; 1.3334x over previous
//
#include <hip/hip_runtime.h>
#include <hip/hip_fp16.h>

// ImplicitPointHead fused (MI355X / gfx950) — round 17: REVERT to r11 optimum.
// Design space fully mapped (r7/r10/r15/r16 = the four corners; all lose):
// 512thr, 8 waves x [32ch x 64pts], PT=64, 2 blocks/CU, prepped f16 weights,
// asm vmcnt B-queue (issue-before-wait), raw barriers with lgkm discipline,
// cross-layer B-prologues, fused L2+L3. Measured 215us (main ~180, prep ~27).

#define NI      128
#define NPTS    2048
#define CH      256
#define NPARAM  263169
#define PT      64
#define NTILES  (NPTS / PT)     // 32
#define ROWS    536             // 67x16B per row (odd -> minimal b128 aliasing)

#define WOFF0   0
#define WOFF1   131072
#define WOFF2   196608
#define WOFF3   262144
#define BOFF0   262400
#define BOFF1   262656
#define BOFF2   262912
#define BOFF3   263168

#define PI_L0   0        // 16 ks * 16 cb * 64 lane * 8
#define PI_L1   131072
#define PI_L2   196608
#define PI_L3   262144
#define WS_PER_INST 262400
#define WS_BYTES ((size_t)NI * WS_PER_INST * 2)

typedef __fp16   h16x2 __attribute__((ext_vector_type(2)));
typedef _Float16 f16x8 __attribute__((ext_vector_type(8)));
typedef float    f32x4 __attribute__((ext_vector_type(4)));

union pack8 { h16x2 h[4]; f16x8 v; };

// ---------------- prep: params fp32 -> fragment-ordered fp16 ----------------
// Frag cb, lane l covers co = (cb>>1)*32 + 2*(l&15) + (cb&1); k = ks*32+(l>>4)*8.
__global__ __launch_bounds__(256) void iph_prep(
    const float* __restrict__ params, _Float16* __restrict__ wsw)
{
    const int inst = blockIdx.y;
    const int r = blockIdx.x * 256 + threadIdx.x;
    if (r >= 32800) return;
    const float* __restrict__ P = params + (size_t)inst * NPARAM;
    _Float16* __restrict__ W = wsw + (size_t)inst * WS_PER_INST;

    int rl, woff, K, dst;
    if (r < 16384)      { rl = r;         woff = WOFF0; K = 512; dst = PI_L0; }
    else if (r < 24576) { rl = r - 16384; woff = WOFF1; K = 256; dst = PI_L1; }
    else if (r < 32768) { rl = r - 24576; woff = WOFF2; K = 256; dst = PI_L2; }
    else {
        const int e = (r - 32768) * 8;
        f16x8 v;
        #pragma unroll
        for (int j = 0; j < 8; ++j) v[j] = (_Float16)P[WOFF3 + e + j];
        *(f16x8*)&W[PI_L3 + e] = v;
        return;
    }
    const int e    = rl * 8;
    const int lane = rl & 63;
    const int cb   = (rl >> 6) & 15;
    const int ks   = rl >> 10;
    const int co   = (cb >> 1) * 32 + 2 * (lane & 15) + (cb & 1);
    const int k    = ks * 32 + (lane >> 4) * 8;
    const float* __restrict__ src = P + woff + co * K + k;
    f16x8 v;
    #pragma unroll
    for (int j = 0; j < 8; ++j) v[j] = (_Float16)src[j];
    *(f16x8*)&W[dst + e] = v;
}

// ---------------- asm pipeline primitives ----------------
__device__ __forceinline__ void issue_b2(const _Float16* p, f16x8& r0, f16x8& r1) {
    const unsigned long long a = (unsigned long long)p;
    asm volatile("global_load_dwordx4 %0, %2, off\n\t"
                 "global_load_dwordx4 %1, %2, off offset:1024"
                 : "=&v"(r0), "=&v"(r1)
                 : "v"(a));
}

template<int N>
__device__ __forceinline__ void wait_vm() {
    if constexpr (N >= 8)      asm volatile("s_waitcnt vmcnt(8)" ::: "memory");
    else if constexpr (N == 6) asm volatile("s_waitcnt vmcnt(6)" ::: "memory");
    else if constexpr (N == 4) asm volatile("s_waitcnt vmcnt(4)" ::: "memory");
    else if constexpr (N == 2) asm volatile("s_waitcnt vmcnt(2)" ::: "memory");
    else                       asm volatile("s_waitcnt vmcnt(0)" ::: "memory");
    __builtin_amdgcn_sched_barrier(0);   // rule #18: keep MFMAs below the wait
}

__device__ __forceinline__ void lgkm0_barrier() {
    asm volatile("s_waitcnt lgkmcnt(0)" ::: "memory");  // publish my LDS writes
    __builtin_amdgcn_s_barrier();                        // raw: vmcnt NOT drained
}

__device__ __forceinline__ void issue_pro(const _Float16* bp, f16x8 (&b0s)[5], f16x8 (&b1s)[5]) {
    #pragma unroll
    for (int i = 0; i < 4; ++i)
        issue_b2(bp + i * 8192, b0s[i], b1s[i]);
}

// ---------------- pipelined GEMM (asm B-queue, 4 ks deep) ----------------
// Requires issue_pro(bp, ...) called earlier (slots 0..3 in flight).
template<int NKS>
__device__ __forceinline__ void gemm_pipe(
    f32x4 (&acc)[4][2], const _Float16* bp, const _Float16* ap,
    f16x8 (&b0s)[5], f16x8 (&b1s)[5])
{
    #pragma unroll
    for (int ks = 0; ks < NKS; ++ks) {
        f16x8 a0 = *(const f16x8*)(ap + ks * 32);
        f16x8 a1 = *(const f16x8*)(ap + 16 * ROWS + ks * 32);
        f16x8 a2 = *(const f16x8*)(ap + 32 * ROWS + ks * 32);
        f16x8 a3 = *(const f16x8*)(ap + 48 * ROWS + ks * 32);
        if (ks + 4 < NKS)
            issue_b2(bp + (ks + 4) * 8192, b0s[(ks + 4) % 5], b1s[(ks + 4) % 5]);
        // in flight: pairs ks .. min(ks+4, NKS-1); wait until pair ks done
        const int rem = NKS - 1 - ks;
        if (rem >= 4)      wait_vm<8>();
        else if (rem == 3) wait_vm<6>();
        else if (rem == 2) wait_vm<4>();
        else if (rem == 1) wait_vm<2>();
        else               wait_vm<0>();
        __builtin_amdgcn_s_setprio(1);
        acc[0][0] = __builtin_amdgcn_mfma_f32_16x16x32_f16(a0, b0s[ks % 5], acc[0][0], 0, 0, 0);
        acc[0][1] = __builtin_amdgcn_mfma_f32_16x16x32_f16(a0, b1s[ks % 5], acc[0][1], 0, 0, 0);
        acc[1][0] = __builtin_amdgcn_mfma_f32_16x16x32_f16(a1, b0s[ks % 5], acc[1][0], 0, 0, 0);
        acc[1][1] = __builtin_amdgcn_mfma_f32_16x16x32_f16(a1, b1s[ks % 5], acc[1][1], 0, 0, 0);
        acc[2][0] = __builtin_amdgcn_mfma_f32_16x16x32_f16(a2, b0s[ks % 5], acc[2][0], 0, 0, 0);
        acc[2][1] = __builtin_amdgcn_mfma_f32_16x16x32_f16(a2, b1s[ks % 5], acc[2][1], 0, 0, 0);
        acc[3][0] = __builtin_amdgcn_mfma_f32_16x16x32_f16(a3, b0s[ks % 5], acc[3][0], 0, 0, 0);
        acc[3][1] = __builtin_amdgcn_mfma_f32_16x16x32_f16(a3, b1s[ks % 5], acc[3][1], 0, 0, 0);
        __builtin_amdgcn_s_setprio(0);
    }
}

// ---------------- main fused kernel ----------------
template<bool PREPPED>
__global__ __launch_bounds__(512, 4) void iph_main(
    const float* __restrict__ feat,     // [128][256][2048]
    const float* __restrict__ coords,   // [128][2048][2]
    const float* __restrict__ params,   // [128][263169]
    const _Float16* __restrict__ wsw,   // fragment-ordered f16 weights
    const float* __restrict__ peg,      // [2][128]
    float* __restrict__ out)            // [128][1][2048]
{
    __shared__ _Float16 X[PT * ROWS];   // 68608 B
    __shared__ float    partial[8][PT]; // 2 KB -> 70.7 KB, 2 blocks/CU

    const int bid  = blockIdx.x;
    const int inst = (bid & 7) | ((bid >> 8) << 3);
    const int tile = (bid >> 3) & 31;
    const int p0   = tile * PT;
    const int tid  = threadIdx.x;
    const int lane = tid & 63;
    const int wave = tid >> 6;
    const int l15  = lane & 15;
    const int hi   = lane >> 4;
    const float* __restrict__ P = params + (size_t)inst * NPARAM;
    const _Float16* __restrict__ WI = wsw + (size_t)inst * WS_PER_INST;

    const _Float16* bp0 = WI + PI_L0 + ((wave * 2) * 64 + lane) * 8;
    const _Float16* bp1 = WI + PI_L1 + ((wave * 2) * 64 + lane) * 8;
    const _Float16* bp2 = WI + PI_L2 + ((wave * 2) * 64 + lane) * 8;
    const _Float16* ap  = &X[l15 * ROWS + hi * 8];

    f16x8 s0[5], s1[5], t0[5], t1[5], u0[5], u1[5];

    // ---- L0 B-prologue at kernel top: flies during PE + staging
    if (PREPPED) issue_pro(bp0, s0, s1);

    // ---- positional encoding -> X[pt][0..255], b128 writes
    {
        const int pt   = tid >> 3;     // 64 pts
        const int part = tid & 7;      // 16 freqs each
        const float2 cc = *(const float2*)&coords[((size_t)inst * NPTS + p0 + pt) * 2];
        const float a = 2.f * cc.x - 1.f;
        const float b = 2.f * cc.y - 1.f;
        float sv[16], cv[16];
        #pragma unroll
        for (int j = 0; j < 16; ++j) {
            const int f = part * 16 + j;
            float locr = a * peg[f] + b * peg[128 + f];
            locr -= floorf(locr);                        // period-1 reduction
            sv[j] = __builtin_amdgcn_sinf(locr);         // sin(2*pi*x)
            cv[j] = __builtin_amdgcn_cosf(locr);
        }
        pack8 q0, q1, c0, c1;
        #pragma unroll
        for (int q = 0; q < 4; ++q) {
            q0.h[q] = __builtin_amdgcn_cvt_pkrtz(sv[2*q],     sv[2*q + 1]);
            q1.h[q] = __builtin_amdgcn_cvt_pkrtz(sv[8 + 2*q], sv[9 + 2*q]);
            c0.h[q] = __builtin_amdgcn_cvt_pkrtz(cv[2*q],     cv[2*q + 1]);
            c1.h[q] = __builtin_amdgcn_cvt_pkrtz(cv[8 + 2*q], cv[9 + 2*q]);
        }
        _Float16* base = &X[pt * ROWS + part * 16];
        *(f16x8*)(base)           = q0.v;
        *(f16x8*)(base + 8)       = q1.v;
        *(f16x8*)(base + 128)     = c0.v;
        *(f16x8*)(base + 136)     = c1.v;
    }
    // ---- features -> X[pt][256..511], 8 dword loads -> one b128 write
    {
        const float* fbase = feat + (size_t)inst * CH * NPTS + p0 + lane;
        #pragma unroll
        for (int s = 0; s < 4; ++s) {
            const int c0i = s * 64 + wave * 8;
            float w8[8];
            #pragma unroll
            for (int j = 0; j < 8; ++j)
                w8[j] = fbase[(size_t)(c0i + j) * NPTS];
            pack8 pk;
            #pragma unroll
            for (int q = 0; q < 4; ++q)
                pk.h[q] = __builtin_amdgcn_cvt_pkrtz(w8[2*q], w8[2*q + 1]);
            *(f16x8*)&X[lane * ROWS + 256 + c0i] = pk.v;
        }
    }
    lgkm0_barrier();   // publish X; raw barrier keeps L0 prologue in flight

    auto write_epilogue = [&](f32x4 (&acc)[4][2], const float2 bb) {
        #pragma unroll
        for (int mt = 0; mt < 4; ++mt) {
            #pragma unroll
            for (int r = 0; r < 4; ++r) {
                // C/D layout (m89): col=lane&15, row=(lane>>4)*4+r
                const float v0 = fmaxf(acc[mt][0][r] + bb.x, 0.f);
                const float v1 = fmaxf(acc[mt][1][r] + bb.y, 0.f);
                const h16x2 e = __builtin_amdgcn_cvt_pkrtz(v0, v1);
                const int pt = mt * 16 + hi * 4 + r;
                *(h16x2*)&X[pt * ROWS + wave * 32 + 2 * l15] = e;
            }
        }
    };

    // fallback inner loop (no prep): r6 simple path
    auto gemm_simple = [&](f32x4 (&acc)[4][2], const float* pw, const int K) {
        for (int ks = 0; ks < (K >> 5); ++ks) {
            f16x8 bfrag[2];
            #pragma unroll
            for (int nt = 0; nt < 2; ++nt) {
                const int co = wave * 32 + 2 * l15 + nt;
                const float* wp = pw + (size_t)co * K + ks * 32 + hi * 8;
                float w8[8];
                __builtin_memcpy(w8, wp, 32);
                f16x8 bb;
                #pragma unroll
                for (int j = 0; j < 8; ++j) bb[j] = (_Float16)w8[j];
                bfrag[nt] = bb;
            }
            f16x8 afrag[4];
            #pragma unroll
            for (int mt = 0; mt < 4; ++mt)
                afrag[mt] = *(const f16x8*)&X[(mt * 16 + l15) * ROWS + ks * 32 + hi * 8];
            #pragma unroll
            for (int mt = 0; mt < 4; ++mt)
                #pragma unroll
                for (int nt = 0; nt < 2; ++nt)
                    acc[mt][nt] = __builtin_amdgcn_mfma_f32_16x16x32_f16(
                        afrag[mt], bfrag[nt], acc[mt][nt], 0, 0, 0);
        }
    };

    // ---- L0
    {
        f32x4 acc[4][2];
        #pragma unroll
        for (int mt = 0; mt < 4; ++mt)
            #pragma unroll
            for (int nt = 0; nt < 2; ++nt)
                acc[mt][nt] = (f32x4){0.f, 0.f, 0.f, 0.f};
        const float2 bb = *(const float2*)&P[BOFF0 + wave * 32 + 2 * l15];
        if (PREPPED) gemm_pipe<16>(acc, bp0, ap, s0, s1);
        else         gemm_simple(acc, P + WOFF0, 512);
        if (PREPPED) issue_pro(bp1, t0, t1);   // L1 prologue flies over epilogue
        __builtin_amdgcn_s_barrier();           // reads of X consumed by all
        write_epilogue(acc, bb);
        lgkm0_barrier();                        // publish L0 output
    }
    // ---- L1
    {
        f32x4 acc[4][2];
        #pragma unroll
        for (int mt = 0; mt < 4; ++mt)
            #pragma unroll
            for (int nt = 0; nt < 2; ++nt)
                acc[mt][nt] = (f32x4){0.f, 0.f, 0.f, 0.f};
        const float2 bb = *(const float2*)&P[BOFF1 + wave * 32 + 2 * l15];
        if (PREPPED) gemm_pipe<8>(acc, bp1, ap, t0, t1);
        else         gemm_simple(acc, P + WOFF1, 256);
        if (PREPPED) issue_pro(bp2, u0, u1);   // L2 prologue
        __builtin_amdgcn_s_barrier();
        write_epilogue(acc, bb);
        lgkm0_barrier();
    }
    // ---- L2 + L3 fused
    {
        f32x4 acc[4][2];
        #pragma unroll
        for (int mt = 0; mt < 4; ++mt)
            #pragma unroll
            for (int nt = 0; nt < 2; ++nt)
                acc[mt][nt] = (f32x4){0.f, 0.f, 0.f, 0.f};
        const float2 bb = *(const float2*)&P[BOFF2 + wave * 32 + 2 * l15];
        const float2 w3 = *(const float2*)&P[WOFF3 + wave * 32 + 2 * l15];
        if (PREPPED) gemm_pipe<8>(acc, bp2, ap, u0, u1);
        else         gemm_simple(acc, P + WOFF2, 256);
        #pragma unroll
        for (int mt = 0; mt < 4; ++mt) {
            #pragma unroll
            for (int r = 0; r < 4; ++r) {
                const float v0 = fmaxf(acc[mt][0][r] + bb.x, 0.f);
                const float v1 = fmaxf(acc[mt][1][r] + bb.y, 0.f);
                float s = v0 * w3.x + v1 * w3.y;
                s += __shfl_xor(s, 1);
                s += __shfl_xor(s, 2);
                s += __shfl_xor(s, 4);
                s += __shfl_xor(s, 8);
                if (l15 == 0)
                    partial[wave][mt * 16 + hi * 4 + r] = s;
            }
        }
        lgkm0_barrier();                        // publish partials
        if (tid < PT) {
            float s = P[BOFF3];
            #pragma unroll
            for (int w = 0; w < 8; ++w) s += partial[w][tid];
            out[(size_t)inst * NPTS + p0 + tid] = s;
        }
    }
}

extern "C" void kernel_launch(void* const* d_in, const int* in_sizes, int n_in,
                              void* d_out, int out_size, void* d_ws, size_t ws_size,
                              hipStream_t stream) {
    (void)in_sizes; (void)n_in; (void)out_size;
    const float* feat   = (const float*)d_in[0];
    const float* coords = (const float*)d_in[1];
    const float* params = (const float*)d_in[2];
    const float* peg    = (const float*)d_in[3];
    float* out = (float*)d_out;

    dim3 grid(NI * NTILES);   // 4096 blocks
    dim3 block(512);

    if (ws_size >= WS_BYTES) {
        _Float16* wsw = (_Float16*)d_ws;
        iph_prep<<<dim3(129, 128), dim3(256), 0, stream>>>(params, wsw);
        iph_main<true><<<grid, block, 0, stream>>>(feat, coords, params, wsw, peg, out);
    } else {
        iph_main<false><<<grid, block, 0, stream>>>(feat, coords, params,
                                                    (const _Float16*)d_ws, peg, out);
    }
}